// Round 9
// baseline (257.274 us; speedup 1.0000x reference)
//
#include <hip/hip_runtime.h>
#include <hip/hip_bf16.h>

#define TT 36
#define KK 160
#define NPOLE 40
#define PP 4096
#define MAXIT 100
#define COLS 16    // columns per group
#define NG 2       // independent groups per block
#define NWPG 5     // waves per group (rows 32/wave); == number of k-chunks
#define NW 10
#define NTHR 640
#define YS 344     // shorts per col: [hi 0..159][pad][lo at +168][pad]
#define GRID 256

// ws float offsets
#define WS_LINV  0
#define WS_LAMBD 1
#define WS_TTS   2
#define WS_KSTAR 128
#define WS_FROB  132
#define WS_CONVF 256
#define WS_D     512
#define WS_A     6400
#define WS_AH    32000
#define WS_AL    44800
#define WS_PART2 57600  // [it][bid] 100*256 floats

typedef float  floatx4 __attribute__((ext_vector_type(4)));
typedef short  shortx8 __attribute__((ext_vector_type(8)));

__device__ __forceinline__ short f2bf(float v) {
  unsigned u = __float_as_uint(v);
  unsigned r = (u + 0x7FFFu + ((u >> 16) & 1u)) >> 16;  // RNE
  return (short)r;
}
__device__ __forceinline__ float bf2f(short s) {
  return __uint_as_float(((unsigned)(unsigned short)s) << 16);
}

__device__ __forceinline__ float wave_sum_dpp(float v) {
#define DPP_ADD(ctrl) \
  v += __int_as_float(__builtin_amdgcn_update_dpp(0, __float_as_int(v), ctrl, 0xf, 0xf, true))
  DPP_ADD(0x111);
  DPP_ADD(0x112);
  DPP_ADD(0x114);
  DPP_ADD(0x118);
  DPP_ADD(0x142);
  DPP_ADD(0x143);
#undef DPP_ADD
  return __int_as_float(__builtin_amdgcn_readlane(__float_as_int(v), 63));
}

__global__ void setup1(const float* __restrict__ Drr,
                       const float* __restrict__ Dth,
                       float* __restrict__ ws) {
  __shared__ float Dl[TT * KK];
  __shared__ float Gl[KK];
  const int tid = threadIdx.x;
  if (tid == 0) ws[WS_FROB] = 0.f;

  for (int idx = tid; idx < TT * KK; idx += 256) {
    int i = idx / KK, k = idx % KK;
    int g = k / NPOLE, n = k % NPOLE;
    float rr = Drr[n], th = Dth[n];
    float pr = powf(rr, (float)i);
    float ang = (float)i * th;
    float tri = (g < 2) ? cosf(ang) : sinf(ang);
    float sgn = ((g & 1) && (i & 1)) ? -1.0f : 1.0f;
    Dl[idx] = pr * tri * sgn;
  }
  __syncthreads();
  if (tid < KK) {
    float s = 0.f;
    for (int i = 0; i < TT; i++) { float v = Dl[i * KK + tid]; s += v * v; }
    float gn = sqrtf(s);
    Gl[tid] = (gn == 0.f) ? sqrtf((float)TT) : gn;
  }
  __syncthreads();
  for (int idx = tid; idx < TT * KK; idx += 256)
    ws[WS_D + idx] = Dl[idx] / Gl[idx % KK];

  if (tid == 0) {
    double ts = 1.0;
    for (int k = 0; k < MAXIT; k++) {
      double tn = (1.0 + sqrt(1.0 + 4.0 * ts * ts)) * 0.5;
      ws[WS_TTS + k] = (float)((ts - 1.0) / tn);
      ts = tn;
    }
  }
}

__global__ void setup2(float* __restrict__ ws) {
  __shared__ float red[256];
  const int a = blockIdx.x, b = threadIdx.x;
  const float* D = &ws[WS_D];
  float ss = 0.f;
  if (b < KK) {
    float s = 0.f;
    for (int t = 0; t < TT; t++) s += D[t * KK + a] * D[t * KK + b];
    ws[WS_A + a * KK + b] = s;
    ss = s * s;
  }
  red[b] = ss;
  __syncthreads();
  for (int off = 128; off > 0; off >>= 1) {
    if (b < off) red[b] += red[b + off];
    __syncthreads();
  }
  if (b == 0) atomicAdd(&ws[WS_FROB], red[0]);
}

__global__ void setup3(float* __restrict__ ws) {
  const int idx = blockIdx.x * 256 + threadIdx.x;
  const float linv = 1.0f / sqrtf(ws[WS_FROB]);
  short* AHs = (short*)&ws[WS_AH];
  short* ALs = (short*)&ws[WS_AL];
  if (idx < KK * KK) {
    int a = idx / KK, b = idx % KK;
    float av = ((a == b) ? 1.0f : 0.0f) - ws[WS_A + idx] * linv;
    short h = f2bf(av);
    AHs[idx] = h;
    ALs[idx] = f2bf(av - bf2f(h));
  }
  if (idx == 0) { ws[WS_LINV] = linv; ws[WS_LAMBD] = 0.1f * linv; }
}

// Block: 2 independent 16-col groups of 5 waves (32 rows/wave).
// Fine-grained producer/consumer: wave v alone produces y-chunk kc=v
// (rows 32v..32v+31, all cols). flag[g][v] = # iterations published.
// Consumers poll flag[kc] >= it per chunk, processing chunks in ring
// order starting at their own chunk (always ready). Double-buffer safety
// is implied by the read-side checks (see proof in round notes).
__global__ __launch_bounds__(NTHR, 2)
void fista_kernel(const float* __restrict__ x, float* __restrict__ out,
                  float* __restrict__ ws, int mode) {
  __shared__ __align__(16) short ys[NG][2][COLS * YS];  // 44,032 B
  __shared__ float wred[NW][MAXIT];
  __shared__ float ttsl[MAXIT];
  __shared__ int flag[NG][NWPG];

  int niter = MAXIT;
  if (mode == 1) {
    int kstar = *(const int*)&ws[WS_KSTAR];
    if (kstar >= MAXIT - 1) return;
    niter = kstar + 1;
  }

  const int tid  = threadIdx.x;
  const int w    = tid >> 6;
  const int lane = tid & 63;
  const int quad = lane >> 4;
  const int l16  = lane & 15;
  const int g    = w / NWPG;       // group 0/1
  const int v    = w % NWPG;       // rowgroup: rows 32v..32v+31 == chunk v
  const int bid  = blockIdx.x;
  const int bb   = (bid * 32) / PP;
  const int p0   = (bid * 32) % PP + 16 * g;
  const float linv  = ws[WS_LINV];
  const float lambd = ws[WS_LAMBD];

  for (int i = tid; i < MAXIT; i += NTHR) ttsl[i] = ws[WS_TTS + i];

  // A fragments in registers, ROTATED: slot j holds k-chunk (v+j)%5
  const short* AH = (const short*)&ws[WS_AH];
  const short* AL = (const short*)&ws[WS_AL];
  shortx8 ah[2][5], al[2][5];
  int kcof[5];
#pragma unroll
  for (int j = 0; j < 5; j++) {
    int kc = v + j; if (kc >= 5) kc -= 5;
    kcof[j] = kc;
#pragma unroll
    for (int rs = 0; rs < 2; rs++) {
      int off = (32 * v + 16 * rs + l16) * KK + 32 * kc + 8 * quad;
      ah[rs][j] = *(const shortx8*)&AH[off];
      al[rs][j] = *(const shortx8*)&AL[off];
    }
  }

  // dty (scaled by linv): rows 32v+16rs+4quad+r, col l16 of this group
  const float* Dg = &ws[WS_D];
  float dty[2][4] = {{0.f,0.f,0.f,0.f},{0.f,0.f,0.f,0.f}};
  {
    const float* xcol = &x[(size_t)bb * TT * PP + p0 + l16];
    for (int t = 0; t < TT; t++) {
      float xv = xcol[(size_t)t * PP];
      float4 d0 = *(const float4*)&Dg[t * KK + 32 * v + 4 * quad];
      float4 d1 = *(const float4*)&Dg[t * KK + 32 * v + 16 + 4 * quad];
      dty[0][0] = fmaf(d0.x, xv, dty[0][0]);
      dty[0][1] = fmaf(d0.y, xv, dty[0][1]);
      dty[0][2] = fmaf(d0.z, xv, dty[0][2]);
      dty[0][3] = fmaf(d0.w, xv, dty[0][3]);
      dty[1][0] = fmaf(d1.x, xv, dty[1][0]);
      dty[1][1] = fmaf(d1.y, xv, dty[1][1]);
      dty[1][2] = fmaf(d1.z, xv, dty[1][2]);
      dty[1][3] = fmaf(d1.w, xv, dty[1][3]);
    }
#pragma unroll
    for (int rs = 0; rs < 2; rs++)
#pragma unroll
      for (int r = 0; r < 4; r++) dty[rs][r] *= linv;
  }

  {
    int* z = (int*)&ys[0][0][0];
    for (int i = tid; i < NG * 2 * COLS * YS / 2; i += NTHR) z[i] = 0;
    if (tid < NG * NWPG) flag[tid / NWPG][tid % NWPG] = 0;
  }
  float xo[2][4] = {{0.f,0.f,0.f,0.f},{0.f,0.f,0.f,0.f}};
  __syncthreads();

  for (int it = 0; it < niter; it++) {
    const short* yb = &ys[g][it & 1][0];
    const int cb = l16 * YS + 8 * quad;
    floatx4 accM[2] = {{dty[0][0], dty[0][1], dty[0][2], dty[0][3]},
                       {dty[1][0], dty[1][1], dty[1][2], dty[1][3]}};
    floatx4 accB[2] = {{0.f,0.f,0.f,0.f},{0.f,0.f,0.f,0.f}};
    floatx4 accC[2] = {{0.f,0.f,0.f,0.f},{0.f,0.f,0.f,0.f}};
#pragma unroll
    for (int j = 0; j < 5; j++) {
      const int kc = kcof[j];
      if (j > 0 && it > 0) {  // own chunk (j==0) is always ready
        while (__atomic_load_n(&flag[g][kc], __ATOMIC_ACQUIRE) < it) { }
      }
      shortx8 bh = *(const shortx8*)&yb[cb + 32 * kc];
      shortx8 bl = *(const shortx8*)&yb[cb + 32 * kc + 168];
#pragma unroll
      for (int rs = 0; rs < 2; rs++) {
        accM[rs] = __builtin_amdgcn_mfma_f32_16x16x32_bf16(ah[rs][j], bh, accM[rs], 0, 0, 0);
        accB[rs] = __builtin_amdgcn_mfma_f32_16x16x32_bf16(ah[rs][j], bl, accB[rs], 0, 0, 0);
        accC[rs] = __builtin_amdgcn_mfma_f32_16x16x32_bf16(al[rs][j], bh, accC[rs], 0, 0, 0);
      }
    }

    const float tt = ttsl[it];
    short* yw = &ys[g][(it & 1) ^ 1][0];
    float lsum = 0.f;
#pragma unroll
    for (int rs = 0; rs < 2; rs++) {
      float yn[4];
#pragma unroll
      for (int r = 0; r < 4; r++) {
        float vv = accM[rs][r] + accB[rs][r] + accC[rs][r];
        float aa = fabsf(vv) - lambd;
        float xv = (aa > 0.f) ? ((vv < 0.f) ? -aa : aa) : 0.f;
        float dd = xv - xo[rs][r];
        lsum = fmaf(dd, dd, lsum);
        yn[r] = fmaf(tt, dd, xv);
        xo[rs][r] = xv;
      }
      __hip_bfloat162 h01 = __float22bfloat162_rn(make_float2(yn[0], yn[1]));
      __hip_bfloat162 h23 = __float22bfloat162_rn(make_float2(yn[2], yn[3]));
      unsigned u01 = *(unsigned*)&h01;
      unsigned u23 = *(unsigned*)&h23;
      float r0f = yn[0] - __uint_as_float(u01 << 16);
      float r1f = yn[1] - __uint_as_float(u01 & 0xffff0000u);
      float r2f = yn[2] - __uint_as_float(u23 << 16);
      float r3f = yn[3] - __uint_as_float(u23 & 0xffff0000u);
      __hip_bfloat162 l01 = __float22bfloat162_rn(make_float2(r0f, r1f));
      __hip_bfloat162 l23 = __float22bfloat162_rn(make_float2(r2f, r3f));
      const int ko = l16 * YS + 32 * v + 16 * rs + 4 * quad;
      *(uint2*)&yw[ko]       = make_uint2(u01, u23);
      *(uint2*)&yw[ko + 168] = make_uint2(*(unsigned*)&l01, *(unsigned*)&l23);
    }

    // publish chunk v of y_{it+1} (release orders the ds_writes above)
    __atomic_store_n(&flag[g][v], it + 1, __ATOMIC_RELEASE);

    if (mode == 0) {
      float wsum = wave_sum_dpp(lsum);   // off the inter-wave critical path
      if (lane == 0) wred[w][it] = wsum;
    }
  }

#pragma unroll
  for (int rs = 0; rs < 2; rs++)
#pragma unroll
    for (int r = 0; r < 4; r++)
      out[((size_t)bb * KK + 32 * v + 16 * rs + 4 * quad + r) * PP + p0 + l16] = xo[rs][r];

  if (mode == 0) {
    __syncthreads();   // all wred slots complete
    for (int it = tid; it < MAXIT; it += NTHR) {
      float s = 0.f;
#pragma unroll
      for (int i = 0; i < NW; i++) s += wred[i][it];
      ws[WS_PART2 + it * GRID + bid] = s;
    }
  }
}

__global__ void conv_reduce(float* __restrict__ ws) {
  __shared__ float red[GRID];
  const int it = blockIdx.x, tid = threadIdx.x;
  red[tid] = ws[WS_PART2 + it * GRID + tid];
  __syncthreads();
  for (int off = GRID / 2; off > 0; off >>= 1) {
    if (tid < off) red[tid] += red[tid + off];
    __syncthreads();
  }
  if (tid == 0) {
    float denom = (it == 0) ? 4096.0f : 160.0f;
    ws[WS_CONVF + it] = (sqrtf(red[0]) / denom < 1e-4f) ? 1.0f : 0.0f;
  }
}

__global__ void conv_scan(float* __restrict__ ws) {
  __shared__ unsigned char conv[MAXIT];
  const int tid = threadIdx.x;
  if (tid < MAXIT) conv[tid] = (ws[WS_CONVF + tid] != 0.0f) ? 1 : 0;
  __syncthreads();
  if (tid == 0) {
    int kstar = MAXIT;
    for (int it = 0; it < MAXIT; it++)
      if (conv[it]) { kstar = it; break; }
    *reinterpret_cast<int*>(&ws[WS_KSTAR]) = kstar;
  }
}

extern "C" void kernel_launch(void* const* d_in, const int* in_sizes, int n_in,
                              void* d_out, int out_size, void* d_ws, size_t ws_size,
                              hipStream_t stream) {
  const float* Drr = (const float*)d_in[0];
  const float* Dth = (const float*)d_in[1];
  const float* x   = (const float*)d_in[2];
  float* out = (float*)d_out;
  float* ws  = (float*)d_ws;

  setup1<<<1, 256, 0, stream>>>(Drr, Dth, ws);
  setup2<<<160, 256, 0, stream>>>(ws);
  setup3<<<100, 256, 0, stream>>>(ws);
  fista_kernel<<<GRID, NTHR, 0, stream>>>(x, out, ws, 0);
  conv_reduce<<<MAXIT, GRID, 0, stream>>>(ws);
  conv_scan<<<1, 128, 0, stream>>>(ws);
  fista_kernel<<<GRID, NTHR, 0, stream>>>(x, out, ws, 1);
}